// Round 5
// baseline (20301.036 us; speedup 1.0000x reference)
//
#include <hip/hip_runtime.h>
#include <stdint.h>

#define RES     1024
#define INPD    16
#define OUTD    8
#define BATCH   32
#define SEQ     4096
#define NCMAX   24             // capacity: 24 chunks * 8 = 192 slots/row
#define PASSPAD 3              // first 3 passes per bank are exact Latin-square
#define GROUP   4              // blocks per batch element
#define NBLK    (BATCH * GROUP)
#define KMAX    6              // per-thread chunk capacity (seg-strided: 6*4=24)

// ws layout:
//   mat:  u32 [NCMAX][1024][8]   packed (col<<18)|bf16(val); pads val=0
//   eff:  u32 [1024]
//   perm: u32 [1024]
//   wnc:  u32 [16]
//   cnt:  u32 [NBLK]             monotonic step counters
//   pub:  f32 [2][BATCH][RES]    parity-buffered h in SORTED space
#define MAT_BYTES ((size_t)NCMAX * RES * 8 * 4)   // 786432

// ---------------------------------------------------------------------------
__global__ __launch_bounds__(32) void esn_count(const float* __restrict__ W,
                                                uint32_t* __restrict__ eff) {
  const int r = blockIdx.x, b = threadIdx.x;
  const float* row = W + (size_t)r * RES;
  int n = 0;
  for (int k = 0; k < 32; ++k) n += (row[b + 32 * k] != 0.0f) ? 1 : 0;
  int t3 = (n > PASSPAD) ? (n - PASSPAD) : 0;
  for (int o = 16; o; o >>= 1) t3 += __shfl_down(t3, o, 32);
  if (b == 0) eff[r] = (uint32_t)(PASSPAD * 32 + t3);
}

// ---------------------------------------------------------------------------
__global__ __launch_bounds__(1024) void esn_sort(const uint32_t* __restrict__ eff,
                                                 uint32_t* __restrict__ perm,
                                                 uint32_t* __restrict__ wnc) {
  __shared__ uint32_t key[RES];
  const int tid = threadIdx.x;
  key[tid] = (eff[tid] << 10) | (uint32_t)tid;
  __syncthreads();
  for (int len = 2; len <= RES; len <<= 1) {
    for (int s = len >> 1; s > 0; s >>= 1) {
      const int j = tid ^ s;
      if (j > tid) {
        const uint32_t a = key[tid], c = key[j];
        const bool up = ((tid & len) == 0);
        if ((a > c) == up) { key[tid] = c; key[j] = a; }
      }
      __syncthreads();
    }
  }
  const uint32_t k = key[tid];                  // ascending by eff
  perm[tid] = k & 1023u;
  if ((tid & 63) == 63) {
    uint32_t c = ((k >> 10) + 7u) >> 3;
    wnc[tid >> 6] = (c < (uint32_t)NCMAX) ? c : (uint32_t)NCMAX;
  }
}

// ---------------------------------------------------------------------------
__global__ __launch_bounds__(32) void esn_pack(const float* __restrict__ W,
                                               const uint32_t* __restrict__ perm,
                                               uint32_t* __restrict__ mato) {
  const int p = blockIdx.x;
  const int b = threadIdx.x;
  __shared__ float    vls[32][16];
  __shared__ uint16_t cls[32][16];
  __shared__ int      cnt[32];
  __shared__ uint32_t rr;
  if (b == 0) rr = perm[p];
  __syncthreads();
  const float* row = W + (size_t)rr * RES;

  int n = 0;
  for (int k = 0; k < 32; ++k) {
    const float v = row[b + 32 * k];
    if (v != 0.0f && n < 16) { vls[b][n] = v; cls[b][n] = (uint16_t)(b + 32 * k); ++n; }
  }
  cnt[b] = n;
  const int rot = p & 31;
  for (int e = b; e < NCMAX * 8; e += 32) {
    const uint32_t padcol = (uint32_t)((rot + (e & 31)) & 31);
    mato[(size_t)(e >> 3) * (RES * 8) + (size_t)p * 8 + (e & 7)] = padcol << 18;
  }
  __syncthreads();

  const int myord = (b - rot) & 31;
  for (int k2 = 0; k2 < n; ++k2) {
    int rank;
    if (k2 < PASSPAD) {
      rank = k2 * 32 + myord;
    } else {
      rank = PASSPAD * 32;
      const int kp = k2 - PASSPAD;
      for (int b2 = 0; b2 < 32; ++b2) {
        int cp = cnt[b2] - PASSPAD; cp = (cp > 0) ? cp : 0;
        const int ord = (b2 - rot) & 31;
        const int lim = kp + ((ord < myord) ? 1 : 0);
        rank += (cp < lim) ? cp : lim;
      }
    }
    if (rank < NCMAX * 8) {
      const uint32_t u  = __float_as_uint(vls[b][k2]);
      const uint32_t bf = (u + 0x7FFFu + ((u >> 16) & 1u)) >> 16;   // RNE bf16
      mato[(size_t)(rank >> 3) * (RES * 8) + (size_t)p * 8 + (rank & 7)] =
          ((uint32_t)cls[b][k2] << 18) | bf;
    }
  }
}

__global__ void esn_init(uint32_t* __restrict__ cnt) {
  if (threadIdx.x < NBLK) cnt[threadIdx.x] = 0;
}

// ---------------------------------------------------------------------------
// Scan: GROUP=4 blocks per batch. Matrix in VGPRs (4 threads/row, seg-strided
// chunks, compile-time-indexed). h full in each block's LDS; exchange via
// cache-bypassing agent atomics in sorted space; acquire only on the flag.
// ---------------------------------------------------------------------------
#define GATHER8(QA, QB)                                                       \
  a0 = fmaf(__uint_as_float((QA).x << 16), hc[(QA).x >> 18], a0);             \
  a1 = fmaf(__uint_as_float((QA).y << 16), hc[(QA).y >> 18], a1);             \
  a2 = fmaf(__uint_as_float((QA).z << 16), hc[(QA).z >> 18], a2);             \
  a3 = fmaf(__uint_as_float((QA).w << 16), hc[(QA).w >> 18], a3);             \
  a0 = fmaf(__uint_as_float((QB).x << 16), hc[(QB).x >> 18], a0);             \
  a1 = fmaf(__uint_as_float((QB).y << 16), hc[(QB).y >> 18], a1);             \
  a2 = fmaf(__uint_as_float((QB).z << 16), hc[(QB).z >> 18], a2);             \
  a3 = fmaf(__uint_as_float((QB).w << 16), hc[(QB).w >> 18], a3);

__global__ __launch_bounds__(1024) void esn_scan(
    const float* __restrict__ x, const float* __restrict__ state,
    const float* __restrict__ Win, const float* __restrict__ Woutw,
    const float* __restrict__ Woutb,
    const uint32_t* __restrict__ mat, const uint32_t* __restrict__ perm,
    const uint32_t* __restrict__ wnc,
    uint32_t* __restrict__ cnt, float* __restrict__ pub,
    float* __restrict__ out) {
  __shared__ float hbuf[2][RES];
  __shared__ float4 xbuf[2][INPD / 4];
  __shared__ __align__(16) float psum[256][4];
  __shared__ uint32_t perml[RES];

  const int bid  = blockIdx.x;
  const int grp  = bid >> 2;
  const int role = bid & 3;
  const int tid  = threadIdx.x;
  const int l    = tid & 63;
  const int v    = tid >> 6;            // wave 0..15
  const int seg  = v >> 2;              // chunk stride class 0..3
  const int lw   = v & 3;               // local row-wave 0..3
  const int W    = lw * 4 + role;       // sorted wave this thread serves
  const int p    = W * 64 + l;          // sorted position
  const int row  = (int)perm[p];        // original row id
  const int ncw  = ((int)__builtin_amdgcn_readfirstlane(wnc[W]) + 3 - seg) >> 2;

  perml[tid] = perm[tid];

  // input-projection quarter for this (row, seg)
  const float4 w4 = ((const float4*)(Win + (size_t)row * INPD))[seg];

  // output-projection weights (waves 0..7; wave v owns output v)
  float wo[16];
  const float* wor = Woutw + (size_t)v * RES;
#pragma unroll
  for (int j = 0; j < 16; ++j) wo[j] = (v < OUTD) ? wor[l + 64 * j] : 0.0f;
  const float bw = (v < OUTD) ? Woutb[v] : 0.0f;

  // matrix resident in VGPRs: chunks c = seg + 4k, k < ncw
  uint4 qa[KMAX], qb[KMAX];
#pragma unroll
  for (int k = 0; k < KMAX; ++k) {
    if (k < ncw) {
      const uint32_t* cp = mat + (size_t)(seg + 4 * k) * (RES * 8) + (size_t)p * 8;
      qa[k] = *(const uint4*)cp;
      qb[k] = *(const uint4*)(cp + 4);
    } else {
      qa[k] = make_uint4(0, 0, 0, 0);
      qb[k] = make_uint4(0, 0, 0, 0);
    }
  }

  hbuf[0][tid] = state[(size_t)grp * RES + tid];
  float hreg = (tid < 256) ? state[(size_t)grp * RES + row] : 0.0f;
  const float* xr = x + (size_t)grp * SEQ * INPD;
  if (tid < INPD / 4) xbuf[0][tid] = ((const float4*)xr)[tid];
  __syncthreads();

  for (int t = 0; t < SEQ; ++t) {
    const int par = t & 1;
    const float* hc = hbuf[par];

    // rotating output projection for step t-1
    if (t > 0 && role == ((t - 1) & 3) && v < OUTD) {
      float s = 0.0f;
#pragma unroll
      for (int j = 0; j < 16; ++j) s = fmaf(hc[l + 64 * j], wo[j], s);
#pragma unroll
      for (int d = 1; d < 64; d <<= 1) s += __shfl_xor(s, d);
      if (l == 0) out[((size_t)grp * SEQ + (t - 1)) * OUTD + v] = s + bw;
    }
    // stage x_{t+1}
    if (v == 15 && l < INPD / 4 && t + 1 < SEQ)
      xbuf[par ^ 1][l] = ((const float4*)(xr + (size_t)(t + 1) * INPD))[l];

    // input projection (quarter) + register-matrix gather
    const float4 xv = xbuf[par][seg];
    float a0 = 0.f, a1 = 0.f, a2 = 0.f, a3 = 0.f;
    a0 = fmaf(xv.x, w4.x, a0); a1 = fmaf(xv.y, w4.y, a1);
    a2 = fmaf(xv.z, w4.z, a2); a3 = fmaf(xv.w, w4.w, a3);
#pragma unroll
    for (int k = 0; k < KMAX; ++k) {
      if (k < ncw) { GATHER8(qa[k], qb[k]) }
    }
    psum[lw * 64 + l][seg] = (a0 + a1) + (a2 + a3);
    __syncthreads();                               // b1: psum ready

    float* ppub = pub + ((size_t)(par ^ 1) * BATCH + grp) * RES;
    if (tid < 256) {
      const float4 ps = *(const float4*)&psum[tid][0];
      const float acc = (ps.x + ps.y) + (ps.z + ps.w);
      const float e  = exp2f(acc * 2.885390081777927f);
      const float th = 1.0f - 2.0f * __builtin_amdgcn_rcpf(e + 1.0f);
      const float hn = fmaf(0.7f, th, 0.3f * hreg);
      hreg = hn;
      hbuf[par ^ 1][row] = hn;
      __hip_atomic_store(&ppub[p], hn, __ATOMIC_RELAXED,
                         __HIP_MEMORY_SCOPE_AGENT);
    }
    __syncthreads();                               // b2: publish drained

    if (tid == 0)
      __hip_atomic_store(&cnt[bid], (uint32_t)(t + 1), __ATOMIC_RELEASE,
                         __HIP_MEMORY_SCOPE_AGENT);
    if (tid < GROUP && tid != role) {
      const uint32_t want = (uint32_t)(t + 1);
      while (__hip_atomic_load(&cnt[grp * GROUP + tid], __ATOMIC_ACQUIRE,
                               __HIP_MEMORY_SCOPE_AGENT) < want)
        __builtin_amdgcn_s_sleep(2);
    }
    __syncthreads();                               // b3: peers done

    // copy 12 peer runs into hbuf[par^1] (sorted run -> original row)
    if (v >= 4) {
      const int j  = v - 4;
      const int gg = j / 3, m = j - gg * 3;
      const int ro = m + ((m >= role) ? 1 : 0);
      const int pp = (gg * 4 + ro) * 64 + l;
      const float hv = __hip_atomic_load(&ppub[pp], __ATOMIC_RELAXED,
                                         __HIP_MEMORY_SCOPE_AGENT);
      hbuf[par ^ 1][perml[pp]] = hv;
    }
    __syncthreads();                               // b4: h(t+1) complete
  }

  // tail by role 0: out[SEQ-1] from hbuf[0] (= states[SEQ-1]); final state
  if (role == 0) {
    if (v < OUTD) {
      float s = 0.0f;
#pragma unroll
      for (int j = 0; j < 16; ++j) s = fmaf(hbuf[0][l + 64 * j], wo[j], s);
#pragma unroll
      for (int d = 1; d < 64; d <<= 1) s += __shfl_xor(s, d);
      if (l == 0) out[((size_t)grp * SEQ + (SEQ - 1)) * OUTD + v] = s + bw;
    }
    float* finals = out + (size_t)BATCH * SEQ * OUTD;
    finals[(size_t)grp * RES + tid] = hbuf[0][tid];
  }
}

// ---------------------------------------------------------------------------
extern "C" void kernel_launch(void* const* d_in, const int* in_sizes, int n_in,
                              void* d_out, int out_size, void* d_ws, size_t ws_size,
                              hipStream_t stream) {
  const float* x     = (const float*)d_in[0];
  const float* state = (const float*)d_in[1];
  const float* Win   = (const float*)d_in[2];
  const float* Wres  = (const float*)d_in[3];
  const float* Woutw = (const float*)d_in[4];
  const float* Woutb = (const float*)d_in[5];
  float* out = (float*)d_out;

  uint8_t*  ws   = (uint8_t*)d_ws;
  uint32_t* mat  = (uint32_t*)ws;
  uint32_t* eff  = (uint32_t*)(ws + MAT_BYTES);
  uint32_t* perm = (uint32_t*)(ws + MAT_BYTES + 4096);
  uint32_t* wnc  = (uint32_t*)(ws + MAT_BYTES + 8192);
  uint32_t* cnt  = (uint32_t*)(ws + MAT_BYTES + 12288);
  float*    pub  = (float*)(ws + MAT_BYTES + 16384);

  esn_count<<<RES, 32, 0, stream>>>(Wres, eff);
  esn_sort<<<1, RES, 0, stream>>>(eff, perm, wnc);
  esn_pack<<<RES, 32, 0, stream>>>(Wres, perm, mat);
  esn_init<<<1, 128, 0, stream>>>(cnt);
  esn_scan<<<NBLK, RES, 0, stream>>>(x, state, Win, Woutw, Woutb,
                                     mat, perm, wnc, cnt, pub, out);
}